// Round 2
// baseline (885.419 us; speedup 1.0000x reference)
//
#include <hip/hip_runtime.h>
#include <hip/hip_bf16.h>

#define NPTS 4096
#define BATCH 4
#define KNN 20

// ws float-offset layout (all fp32)
#define OFF_W0S   0       // 384  (w0 * bn0 scale folded)
#define OFF_B0F   384     // 64
#define OFF_S1F   448     // 64
#define OFF_B1F   512     // 64
#define OFF_WOUTS 576     // 192 (w_out * bn_out scale folded)
#define OFF_BOUTF 768     // 3
#define OFF_IDX_BYTES 4096   // ushort idx[16384*20] = 655360 B -> total ~660 KB

__global__ __launch_bounds__(256) void prep_kernel(
    const float* __restrict__ w0, const float* __restrict__ g0, const float* __restrict__ b0,
    const float* __restrict__ g1, const float* __restrict__ b1,
    const float* __restrict__ wout, const float* __restrict__ gout, const float* __restrict__ bout,
    float* __restrict__ wsf) {
  const float rs = 1.0f / sqrtf(1.0f + 1e-5f);
  int t = blockIdx.x * 256 + threadIdx.x;   // grid covers >= 512 threads
  if (t < 384) wsf[OFF_W0S + t] = w0[t] * (g0[t / 6] * rs);
  if (t < 64) {
    wsf[OFF_B0F + t] = b0[t];
    wsf[OFF_S1F + t] = g1[t] * rs;
    wsf[OFF_B1F + t] = b1[t];
  }
  if (t < 192) wsf[OFF_WOUTS + t] = wout[t] * (gout[t / 64] * rs);
  if (t < 3) wsf[OFF_BOUTF + t] = bout[t];
}

// One wave (64 threads) per point: pd[4096] in LDS, 20 rounds of wave-argmax.
__global__ __launch_bounds__(64) void knn_kernel(const float* __restrict__ x,
                                                 unsigned short* __restrict__ idxbuf) {
  __shared__ float pd[NPTS];
  const int pt = blockIdx.x;
  const int b = pt >> 12, n = pt & (NPTS - 1);
  const int lane = threadIdx.x;
  const float* xb = x + b * 3 * NPTS;
  const float xi0 = xb[n];
  const float xi1 = xb[NPTS + n];
  const float xi2 = xb[2 * NPTS + n];
  const float xxi = xi0 * xi0 + xi1 * xi1 + xi2 * xi2;
  for (int s = 0; s < NPTS / 64; ++s) {
    int j = s * 64 + lane;
    float xj0 = xb[j], xj1 = xb[NPTS + j], xj2 = xb[2 * NPTS + j];
    float dot = xi0 * xj0 + xi1 * xj1 + xi2 * xj2;
    float xxj = xj0 * xj0 + xj1 * xj1 + xj2 * xj2;
    float inner = -2.0f * dot;
    pd[j] = (-xxi - inner) - xxj;   // same assoc as reference
  }
  __syncthreads();
  for (int r = 0; r < KNN; ++r) {
    // 4 independent scan chains for ILP
    float bv0 = -1e30f, bv1 = -1e30f, bv2 = -1e30f, bv3 = -1e30f;
    int bj0 = -1, bj1 = -1, bj2 = -1, bj3 = -1;
    for (int s = 0; s < NPTS / 64; s += 4) {
      int j0 = s * 64 + lane, j1 = j0 + 64, j2 = j0 + 128, j3 = j0 + 192;
      float v0 = pd[j0], v1 = pd[j1], v2 = pd[j2], v3 = pd[j3];
      if (v0 > bv0) { bv0 = v0; bj0 = j0; }   // ascending j + strict > keeps smallest j on tie
      if (v1 > bv1) { bv1 = v1; bj1 = j1; }
      if (v2 > bv2) { bv2 = v2; bj2 = j2; }
      if (v3 > bv3) { bv3 = v3; bj3 = j3; }
    }
    // merge 4 chains with index tie-break
    if ((bv1 > bv0) || (bv1 == bv0 && bj1 < bj0)) { bv0 = bv1; bj0 = bj1; }
    if ((bv2 > bv0) || (bv2 == bv0 && bj2 < bj0)) { bv0 = bv2; bj0 = bj2; }
    if ((bv3 > bv0) || (bv3 == bv0 && bj3 < bj0)) { bv0 = bv3; bj0 = bj3; }
    // wave butterfly argmax, tie -> smaller index (matches lax.top_k stability)
    for (int off = 32; off > 0; off >>= 1) {
      float ov = __shfl_xor(bv0, off);
      int oj = __shfl_xor(bj0, off);
      if ((ov > bv0) || (ov == bv0 && oj < bj0)) { bv0 = ov; bj0 = oj; }
    }
    if (lane == 0) {
      idxbuf[pt * KNN + r] = (unsigned short)bj0;
      pd[bj0] = -1e30f;
    }
    __syncthreads();
  }
}

// 2 waves/block, 3 points/wave (lane = (p, e)); h[64] in VGPRs, w1 via uniform scalar loads.
__global__ __launch_bounds__(128) void mlp_kernel(const float* __restrict__ x,
                                                  const float* __restrict__ w1f,
                                                  const float* __restrict__ wsf,
                                                  const unsigned short* __restrict__ idxbuf,
                                                  float* __restrict__ out) {
  __shared__ float zbuf[2][60 * 65];   // [wave][row=p*20+e][o], stride 65: conflict-free
  const int lane = threadIdx.x & 63;
  const int w = threadIdx.x >> 6;
  const int p = lane / 20;       // 0..2 valid, 3 = idle lanes 60..63
  const int e = lane % 20;
  const int pt0 = blockIdx.x * 6 + w * 3;
  const int pt = pt0 + p;
  const bool active = (p < 3) && (pt < BATCH * NPTS);

  float h[64];
  float v6c0 = 0.f, v6c1 = 0.f, v6c2 = 0.f, v6c3 = 0.f, v6c4 = 0.f, v6c5 = 0.f;

  if (active) {
    const int b = pt >> 12, n = pt & (NPTS - 1);
    const float* xb = x + b * 3 * NPTS;
    const float xi0 = xb[n], xi1 = xb[NPTS + n], xi2 = xb[2 * NPTS + n];
    const int j = idxbuf[pt * KNN + e];
    const float xj0 = xb[j], xj1 = xb[NPTS + j], xj2 = xb[2 * NPTS + j];
    v6c0 = xj0 - xi0; v6c1 = xj1 - xi1; v6c2 = xj2 - xi2;
    v6c3 = xi0; v6c4 = xi1; v6c5 = xi2;

    // h[d] = lrelu( (w0*scale0) . v6 + b0 )
#pragma unroll
    for (int d = 0; d < 64; ++d) {
      const float2* w02 = (const float2*)(wsf + OFF_W0S + d * 6);
      float2 a = w02[0], bq = w02[1], c = w02[2];
      float acc = a.x * v6c0 + a.y * v6c1 + bq.x * v6c2 + bq.y * v6c3 + c.x * v6c4 + c.y * v6c5;
      acc += wsf[OFF_B0F + d];
      h[d] = acc >= 0.f ? acc : 0.2f * acc;
    }

    const int zrow = (p * 20 + e) * 65;
#pragma unroll 1
    for (int o = 0; o < 64; ++o) {
      const float4* r4 = (const float4*)(w1f + o * 384);  // rows o*6 .. o*6+5, uniform -> s_load
      float t0 = 0.f, t1 = 0.f, t2 = 0.f, t3 = 0.f, t4 = 0.f, t5 = 0.f;
#pragma unroll
      for (int dq = 0; dq < 16; ++dq) {
        float4 a0 = r4[dq];
        float4 a1 = r4[16 + dq];
        float4 a2 = r4[32 + dq];
        float4 a3 = r4[48 + dq];
        float4 a4 = r4[64 + dq];
        float4 a5 = r4[80 + dq];
        int d = dq * 4;
        t0 += a0.x * h[d] + a0.y * h[d + 1] + a0.z * h[d + 2] + a0.w * h[d + 3];
        t1 += a1.x * h[d] + a1.y * h[d + 1] + a1.z * h[d + 2] + a1.w * h[d + 3];
        t2 += a2.x * h[d] + a2.y * h[d + 1] + a2.z * h[d + 2] + a2.w * h[d + 3];
        t3 += a3.x * h[d] + a3.y * h[d + 1] + a3.z * h[d + 2] + a3.w * h[d + 3];
        t4 += a4.x * h[d] + a4.y * h[d + 1] + a4.z * h[d + 2] + a4.w * h[d + 3];
        t5 += a5.x * h[d] + a5.y * h[d + 1] + a5.z * h[d + 2] + a5.w * h[d + 3];
      }
      float z = t0 * v6c0 + t1 * v6c1 + t2 * v6c2 + t3 * v6c3 + t4 * v6c4 + t5 * v6c5;
      z = z * wsf[OFF_S1F + o] + wsf[OFF_B1F + o];
      z = z >= 0.f ? z : 0.2f * z;
      zbuf[w][zrow + o] = z;
    }
  }
  __syncthreads();

  // phase 4: lane = o; max over k, then fused 3x64 conv + BN + lrelu
  for (int p2 = 0; p2 < 3; ++p2) {
    const int ptv = pt0 + p2;
    if (ptv >= BATCH * NPTS) break;
    float x1 = -1e30f;
#pragma unroll
    for (int ee = 0; ee < KNN; ++ee)
      x1 = fmaxf(x1, zbuf[w][(p2 * 20 + ee) * 65 + lane]);
    const int b = ptv >> 12, n = ptv & (NPTS - 1);
#pragma unroll
    for (int m = 0; m < 3; ++m) {
      float part = wsf[OFF_WOUTS + m * 64 + lane] * x1;
      for (int off = 32; off > 0; off >>= 1) part += __shfl_xor(part, off);
      if (lane == 0) {
        float ov = part + wsf[OFF_BOUTF + m];
        ov = ov >= 0.f ? ov : 0.2f * ov;
        out[(b * 3 + m) * NPTS + n] = ov;
      }
    }
  }
}

extern "C" void kernel_launch(void* const* d_in, const int* in_sizes, int n_in,
                              void* d_out, int out_size, void* d_ws, size_t ws_size,
                              hipStream_t stream) {
  const float* x    = (const float*)d_in[0];
  const float* w0   = (const float*)d_in[1];
  const float* g0   = (const float*)d_in[2];
  const float* b0   = (const float*)d_in[3];
  const float* w1   = (const float*)d_in[4];
  const float* g1   = (const float*)d_in[5];
  const float* b1   = (const float*)d_in[6];
  const float* wout = (const float*)d_in[7];
  const float* gout = (const float*)d_in[8];
  const float* bout = (const float*)d_in[9];
  float* wsf = (float*)d_ws;
  unsigned short* idxbuf = (unsigned short*)((char*)d_ws + OFF_IDX_BYTES);
  float* out = (float*)d_out;

  prep_kernel<<<2, 256, 0, stream>>>(w0, g0, b0, g1, b1, wout, gout, bout, wsf);
  knn_kernel<<<BATCH * NPTS, 64, 0, stream>>>(x, idxbuf);
  mlp_kernel<<<(BATCH * NPTS + 5) / 6, 128, 0, stream>>>(x, w1, wsf, idxbuf, out);
}

// Round 3
// 410.387 us; speedup vs baseline: 2.1575x; 2.1575x over previous
//
#include <hip/hip_runtime.h>
#include <hip/hip_bf16.h>

#define NPTS 4096
#define BATCH 4
#define KNN 20

typedef __attribute__((ext_vector_type(8))) short bf16x8;
typedef __attribute__((ext_vector_type(4))) float f32x4;
typedef __attribute__((ext_vector_type(4))) int i32x4;

// ws layout (bytes):
//   0      : fp32 tables: w0s[384] b0[64] s1[64] b1[64] wouts[192] bout[3]
//   4096   : whi frags ushort[24576]  (B-fragment layout, hi split)
//   53248  : wlo frags ushort[24576]  (lo split)
//   102400 : idxbuf ushort[16384*20]
#define OFF_W0S   0
#define OFF_B0F   384
#define OFF_S1F   448
#define OFF_B1F   512
#define OFF_WOUTS 576
#define OFF_BOUTF 768
#define OFF_WHI_BYTES 4096
#define OFF_WLO_BYTES 53248
#define OFF_IDX_BYTES 102400

__global__ __launch_bounds__(256) void prep_kernel(
    const float* __restrict__ w0, const float* __restrict__ g0, const float* __restrict__ b0,
    const float* __restrict__ w1, const float* __restrict__ g1, const float* __restrict__ b1,
    const float* __restrict__ wout, const float* __restrict__ gout, const float* __restrict__ bout,
    float* __restrict__ wsf, unsigned short* __restrict__ whi, unsigned short* __restrict__ wlo) {
  const float rs = 1.0f / sqrtf(1.0f + 1e-5f);
  int t = blockIdx.x * 256 + threadIdx.x;
  if (t < 384) wsf[OFF_W0S + t] = w0[t] * (g0[t / 6] * rs);
  if (t < 64) {
    wsf[OFF_B0F + t] = b0[t];
    wsf[OFF_S1F + t] = g1[t] * rs;
    wsf[OFF_B1F + t] = b1[t];
  }
  if (t < 192) wsf[OFF_WOUTS + t] = wout[t] * (gout[t / 64] * rs);
  if (t < 3) wsf[OFF_BOUTF + t] = bout[t];
  // B-fragment layout for mfma_f32_16x16x32_bf16: frag ft = kk*4+nt; lane L holds
  // B[k = kk*32 + (L>>4)*8 + j][n = nt*16 + (L&15)], j=0..7 packed consecutively.
  if (t < 24576) {
    int j = t & 7, L = (t >> 3) & 63, ft = t >> 9;
    int kk = ft >> 2, nt = ft & 3;
    int k = kk * 32 + ((L >> 4) << 3) + j;
    int c = k >> 6, d = k & 63;
    int o = nt * 16 + (L & 15);
    float w = w1[(o * 6 + c) * 64 + d];
    unsigned bw = __float_as_uint(w);
    unsigned hb = bw & 0xFFFF0000u;             // exact truncation split
    float r = w - __uint_as_float(hb);
    whi[t] = (unsigned short)(bw >> 16);
    wlo[t] = (unsigned short)(__float_as_uint(r) >> 16);
  }
}

// One wave per point: pd[4096] in LDS, 20 rounds of wave-argmax. (unchanged)
__global__ __launch_bounds__(64) void knn_kernel(const float* __restrict__ x,
                                                 unsigned short* __restrict__ idxbuf) {
  __shared__ float pd[NPTS];
  const int pt = blockIdx.x;
  const int b = pt >> 12, n = pt & (NPTS - 1);
  const int lane = threadIdx.x;
  const float* xb = x + b * 3 * NPTS;
  const float xi0 = xb[n];
  const float xi1 = xb[NPTS + n];
  const float xi2 = xb[2 * NPTS + n];
  const float xxi = xi0 * xi0 + xi1 * xi1 + xi2 * xi2;
  for (int s = 0; s < NPTS / 64; ++s) {
    int j = s * 64 + lane;
    float xj0 = xb[j], xj1 = xb[NPTS + j], xj2 = xb[2 * NPTS + j];
    float dot = xi0 * xj0 + xi1 * xj1 + xi2 * xj2;
    float xxj = xj0 * xj0 + xj1 * xj1 + xj2 * xj2;
    float inner = -2.0f * dot;
    pd[j] = (-xxi - inner) - xxj;
  }
  __syncthreads();
  for (int r = 0; r < KNN; ++r) {
    float bv0 = -1e30f, bv1 = -1e30f, bv2 = -1e30f, bv3 = -1e30f;
    int bj0 = -1, bj1 = -1, bj2 = -1, bj3 = -1;
    for (int s = 0; s < NPTS / 64; s += 4) {
      int j0 = s * 64 + lane, j1 = j0 + 64, j2 = j0 + 128, j3 = j0 + 192;
      float v0 = pd[j0], v1 = pd[j1], v2 = pd[j2], v3 = pd[j3];
      if (v0 > bv0) { bv0 = v0; bj0 = j0; }
      if (v1 > bv1) { bv1 = v1; bj1 = j1; }
      if (v2 > bv2) { bv2 = v2; bj2 = j2; }
      if (v3 > bv3) { bv3 = v3; bj3 = j3; }
    }
    if ((bv1 > bv0) || (bv1 == bv0 && bj1 < bj0)) { bv0 = bv1; bj0 = bj1; }
    if ((bv2 > bv0) || (bv2 == bv0 && bj2 < bj0)) { bv0 = bv2; bj0 = bj2; }
    if ((bv3 > bv0) || (bv3 == bv0 && bj3 < bj0)) { bv0 = bv3; bj0 = bj3; }
    for (int off = 32; off > 0; off >>= 1) {
      float ov = __shfl_xor(bv0, off);
      int oj = __shfl_xor(bj0, off);
      if ((ov > bv0) || (ov == bv0 && oj < bj0)) { bv0 = ov; bj0 = oj; }
    }
    if (lane == 0) {
      idxbuf[pt * KNN + r] = (unsigned short)bj0;
      pd[bj0] = -1e30f;
    }
    __syncthreads();
  }
}

// MFMA mlp: 1 wave/block = 4 points = 80 edges = 5 M-tiles.
// z(E x 64) = u(E x 384) @ W(384 x 64), u[e][c*64+d] = v6[e][c]*h[e][d],
// fp32 emulated via truncation split: 3 bf16 mfmas (hi*hi + hi*lo + lo*hi).
__global__ __launch_bounds__(64) void mlp_kernel(const float* __restrict__ x,
                                                 const float* __restrict__ wsf,
                                                 const unsigned short* __restrict__ whi,
                                                 const unsigned short* __restrict__ wlo,
                                                 const unsigned short* __restrict__ idxbuf,
                                                 float* __restrict__ out) {
  // h: [80][68] fp32 (stride 68: b128 reads 2-way only); pmax [20][66] aliases h.
  // v6: [80][8]
  __shared__ float smem[80 * 68 + 80 * 8];
  float* h_lds = smem;
  float* v6_lds = smem + 80 * 68;
  float* pmax = smem;

  const int lane = threadIdx.x;
  const int quad = lane >> 4, l15 = lane & 15;
  const int pt_base = blockIdx.x * 4;

  // per-lane weight preloads
  const float w0r0 = wsf[OFF_W0S + lane * 6 + 0];
  const float w0r1 = wsf[OFF_W0S + lane * 6 + 1];
  const float w0r2 = wsf[OFF_W0S + lane * 6 + 2];
  const float w0r3 = wsf[OFF_W0S + lane * 6 + 3];
  const float w0r4 = wsf[OFF_W0S + lane * 6 + 4];
  const float w0r5 = wsf[OFF_W0S + lane * 6 + 5];
  const float b0r = wsf[OFF_B0F + lane];
  float s1v[4], b1v[4];
#pragma unroll
  for (int nt = 0; nt < 4; ++nt) {
    s1v[nt] = wsf[OFF_S1F + nt * 16 + l15];
    b1v[nt] = wsf[OFF_B1F + nt * 16 + l15];
  }
  float woutr[3];
#pragma unroll
  for (int m = 0; m < 3; ++m) woutr[m] = wsf[OFF_WOUTS + m * 64 + lane];

  // stage 1: v6 per edge
#pragma unroll
  for (int rep = 0; rep < 2; ++rep) {
    int e = rep * 64 + lane;
    if (e < 80) {
      int p = e / 20;
      int el = e - p * 20;
      int pt = pt_base + p;
      int b = pt >> 12, n = pt & (NPTS - 1);
      const float* xb = x + b * 3 * NPTS;
      float xi0 = xb[n], xi1 = xb[NPTS + n], xi2 = xb[2 * NPTS + n];
      int jn = idxbuf[pt * KNN + el];
      float xj0 = xb[jn], xj1 = xb[NPTS + jn], xj2 = xb[2 * NPTS + jn];
      v6_lds[e * 8 + 0] = xj0 - xi0;
      v6_lds[e * 8 + 1] = xj1 - xi1;
      v6_lds[e * 8 + 2] = xj2 - xi2;
      v6_lds[e * 8 + 3] = xi0;
      v6_lds[e * 8 + 4] = xi1;
      v6_lds[e * 8 + 5] = xi2;
    }
  }
  __syncthreads();

  // stage 2: h[e][d=lane] (writes conflict-free: lane = consecutive d)
#pragma unroll 4
  for (int e = 0; e < 80; ++e) {
    f32x4 va = *(const f32x4*)(v6_lds + e * 8);       // broadcast
    float c4 = v6_lds[e * 8 + 4], c5 = v6_lds[e * 8 + 5];
    float acc = b0r + w0r0 * va.x + w0r1 * va.y + w0r2 * va.z + w0r3 * va.w + w0r4 * c4 + w0r5 * c5;
    h_lds[e * 68 + lane] = fmaxf(acc, 0.2f * acc);    // lrelu
  }
  __syncthreads();

  // k-loop: 12 steps of K=32
  f32x4 acc[5][4];
#pragma unroll
  for (int t = 0; t < 5; ++t)
#pragma unroll
    for (int nt = 0; nt < 4; ++nt) acc[t][nt] = (f32x4){0.f, 0.f, 0.f, 0.f};

  const i32x4* whp = (const i32x4*)whi;
  const i32x4* wlp = (const i32x4*)wlo;
  i32x4 wh[4], wl[4];
#pragma unroll
  for (int nt = 0; nt < 4; ++nt) {
    wh[nt] = whp[nt * 64 + lane];
    wl[nt] = wlp[nt * 64 + lane];
  }

#pragma unroll 2
  for (int kk = 0; kk < 12; ++kk) {
    i32x4 whn[4], wln[4];
    if (kk < 11) {
#pragma unroll
      for (int nt = 0; nt < 4; ++nt) {
        whn[nt] = whp[((kk + 1) * 4 + nt) * 64 + lane];
        wln[nt] = wlp[((kk + 1) * 4 + nt) * 64 + lane];
      }
    }
    const int c = kk >> 1;
    const int d0 = (kk & 1) * 32 + quad * 8;
#pragma unroll
    for (int t = 0; t < 5; ++t) {
      const int m = t * 16 + l15;
      const float* hp = h_lds + m * 68 + d0;
      f32x4 h0 = *(const f32x4*)hp;
      f32x4 h1 = *(const f32x4*)(hp + 4);
      float vc = v6_lds[m * 8 + c];
      float u0 = vc * h0.x, u1 = vc * h0.y, u2 = vc * h0.z, u3 = vc * h0.w;
      float u4 = vc * h1.x, u5 = vc * h1.y, u6 = vc * h1.z, u7 = vc * h1.w;
      unsigned ub0 = __float_as_uint(u0), ub1 = __float_as_uint(u1);
      unsigned ub2 = __float_as_uint(u2), ub3 = __float_as_uint(u3);
      unsigned ub4 = __float_as_uint(u4), ub5 = __float_as_uint(u5);
      unsigned ub6 = __float_as_uint(u6), ub7 = __float_as_uint(u7);
      float r0 = u0 - __uint_as_float(ub0 & 0xFFFF0000u);
      float r1 = u1 - __uint_as_float(ub1 & 0xFFFF0000u);
      float r2 = u2 - __uint_as_float(ub2 & 0xFFFF0000u);
      float r3 = u3 - __uint_as_float(ub3 & 0xFFFF0000u);
      float r4 = u4 - __uint_as_float(ub4 & 0xFFFF0000u);
      float r5 = u5 - __uint_as_float(ub5 & 0xFFFF0000u);
      float r6 = u6 - __uint_as_float(ub6 & 0xFFFF0000u);
      float r7 = u7 - __uint_as_float(ub7 & 0xFFFF0000u);
      i32x4 ah, al;
      ah.x = __builtin_amdgcn_perm(ub1, ub0, 0x07060302);
      ah.y = __builtin_amdgcn_perm(ub3, ub2, 0x07060302);
      ah.z = __builtin_amdgcn_perm(ub5, ub4, 0x07060302);
      ah.w = __builtin_amdgcn_perm(ub7, ub6, 0x07060302);
      al.x = __builtin_amdgcn_perm(__float_as_uint(r1), __float_as_uint(r0), 0x07060302);
      al.y = __builtin_amdgcn_perm(__float_as_uint(r3), __float_as_uint(r2), 0x07060302);
      al.z = __builtin_amdgcn_perm(__float_as_uint(r5), __float_as_uint(r4), 0x07060302);
      al.w = __builtin_amdgcn_perm(__float_as_uint(r7), __float_as_uint(r6), 0x07060302);
      bf16x8 ahv = __builtin_bit_cast(bf16x8, ah);
      bf16x8 alv = __builtin_bit_cast(bf16x8, al);
#pragma unroll
      for (int nt = 0; nt < 4; ++nt) {
        bf16x8 bh = __builtin_bit_cast(bf16x8, wh[nt]);
        bf16x8 bl = __builtin_bit_cast(bf16x8, wl[nt]);
        acc[t][nt] = __builtin_amdgcn_mfma_f32_16x16x32_bf16(ahv, bh, acc[t][nt], 0, 0, 0);
        acc[t][nt] = __builtin_amdgcn_mfma_f32_16x16x32_bf16(ahv, bl, acc[t][nt], 0, 0, 0);
        acc[t][nt] = __builtin_amdgcn_mfma_f32_16x16x32_bf16(alv, bh, acc[t][nt], 0, 0, 0);
      }
    }
#pragma unroll
    for (int nt = 0; nt < 4; ++nt) { wh[nt] = whn[nt]; wl[nt] = wln[nt]; }
  }
  __syncthreads();

  // epilogue: BN + lrelu per z, lane-local max over 4 rows (one quad = 4 edges
  // = always within one point since 20 = 5 quads), transpose via pmax LDS.
  // C layout: row(edge) = quad*4 + reg, col(o) = nt*16 + l15.
#pragma unroll
  for (int t = 0; t < 5; ++t) {
#pragma unroll
    for (int nt = 0; nt < 4; ++nt) {
      f32x4 a = acc[t][nt];
      float z0 = a.x * s1v[nt] + b1v[nt]; z0 = fmaxf(z0, 0.2f * z0);
      float z1 = a.y * s1v[nt] + b1v[nt]; z1 = fmaxf(z1, 0.2f * z1);
      float z2 = a.z * s1v[nt] + b1v[nt]; z2 = fmaxf(z2, 0.2f * z2);
      float z3 = a.w * s1v[nt] + b1v[nt]; z3 = fmaxf(z3, 0.2f * z3);
      float m4 = fmaxf(fmaxf(z0, z1), fmaxf(z2, z3));
      pmax[(t * 4 + quad) * 66 + nt * 16 + l15] = m4;
    }
  }
  __syncthreads();

  // lane = o: max over the point's 5 quad-groups, then fused 3x64 conv
#pragma unroll
  for (int p = 0; p < 4; ++p) {
    float x1 = pmax[(p * 5 + 0) * 66 + lane];
    x1 = fmaxf(x1, pmax[(p * 5 + 1) * 66 + lane]);
    x1 = fmaxf(x1, pmax[(p * 5 + 2) * 66 + lane]);
    x1 = fmaxf(x1, pmax[(p * 5 + 3) * 66 + lane]);
    x1 = fmaxf(x1, pmax[(p * 5 + 4) * 66 + lane]);
    int pt = pt_base + p;
    int b = pt >> 12, n = pt & (NPTS - 1);
#pragma unroll
    for (int m = 0; m < 3; ++m) {
      float part = woutr[m] * x1;
      for (int off = 32; off > 0; off >>= 1) part += __shfl_xor(part, off);
      if (lane == 0) {
        float ov = part + wsf[OFF_BOUTF + m];
        out[(b * 3 + m) * NPTS + n] = fmaxf(ov, 0.2f * ov);
      }
    }
  }
}

extern "C" void kernel_launch(void* const* d_in, const int* in_sizes, int n_in,
                              void* d_out, int out_size, void* d_ws, size_t ws_size,
                              hipStream_t stream) {
  const float* x    = (const float*)d_in[0];
  const float* w0   = (const float*)d_in[1];
  const float* g0   = (const float*)d_in[2];
  const float* b0   = (const float*)d_in[3];
  const float* w1   = (const float*)d_in[4];
  const float* g1   = (const float*)d_in[5];
  const float* b1   = (const float*)d_in[6];
  const float* wout = (const float*)d_in[7];
  const float* gout = (const float*)d_in[8];
  const float* bout = (const float*)d_in[9];
  float* wsf = (float*)d_ws;
  unsigned short* whi = (unsigned short*)((char*)d_ws + OFF_WHI_BYTES);
  unsigned short* wlo = (unsigned short*)((char*)d_ws + OFF_WLO_BYTES);
  unsigned short* idxbuf = (unsigned short*)((char*)d_ws + OFF_IDX_BYTES);
  float* out = (float*)d_out;

  prep_kernel<<<96, 256, 0, stream>>>(w0, g0, b0, w1, g1, b1, wout, gout, bout, wsf, whi, wlo);
  knn_kernel<<<BATCH * NPTS, 64, 0, stream>>>(x, idxbuf);
  mlp_kernel<<<BATCH * NPTS / 4, 64, 0, stream>>>(x, wsf, whi, wlo, idxbuf, out);
}

// Round 4
// 219.322 us; speedup vs baseline: 4.0371x; 1.8712x over previous
//
#include <hip/hip_runtime.h>
#include <hip/hip_bf16.h>

#define NPTS 4096
#define BATCH 4
#define KNN 20

typedef __attribute__((ext_vector_type(8))) short bf16x8;
typedef __attribute__((ext_vector_type(4))) float f32x4;
typedef __attribute__((ext_vector_type(4))) int i32x4;
typedef unsigned long long u64;

// ws layout (bytes):
//   0      : fp32 tables: w0s[384] b0[64] s1[64] b1[64] wouts[192] bout[3]
//   4096   : whi frags ushort[24576]  (B-fragment layout, hi split)
//   53248  : wlo frags ushort[24576]  (lo split)
//   102400 : idxbuf ushort[16384*20]  (655360 B)
//   757760 : xq float4[16384] = (x0,x1,x2,||x||^2)  (262144 B) -> total 1019904
#define OFF_W0S   0
#define OFF_B0F   384
#define OFF_S1F   448
#define OFF_B1F   512
#define OFF_WOUTS 576
#define OFF_BOUTF 768
#define OFF_WHI_BYTES 4096
#define OFF_WLO_BYTES 53248
#define OFF_IDX_BYTES 102400
#define OFF_XQ_BYTES  757760

__device__ __forceinline__ u64 shflx64(u64 v, int off) {
  int lo = __shfl_xor((int)(v & 0xFFFFFFFFull), off);
  int hi = __shfl_xor((int)(v >> 32), off);
  return ((u64)(unsigned)hi << 32) | (unsigned)lo;
}
__device__ __forceinline__ u64 shflbc64(u64 v, int src) {
  int lo = __shfl((int)(v & 0xFFFFFFFFull), src);
  int hi = __shfl((int)(v >> 32), src);
  return ((u64)(unsigned)hi << 32) | (unsigned)lo;
}

__global__ __launch_bounds__(256) void prep_kernel(
    const float* __restrict__ x,
    const float* __restrict__ w0, const float* __restrict__ g0, const float* __restrict__ b0,
    const float* __restrict__ w1, const float* __restrict__ g1, const float* __restrict__ b1,
    const float* __restrict__ wout, const float* __restrict__ gout, const float* __restrict__ bout,
    float* __restrict__ wsf, unsigned short* __restrict__ whi, unsigned short* __restrict__ wlo,
    float4* __restrict__ xq) {
  const float rs = 1.0f / sqrtf(1.0f + 1e-5f);
  int t = blockIdx.x * 256 + threadIdx.x;
  if (t < 384) wsf[OFF_W0S + t] = w0[t] * (g0[t / 6] * rs);
  if (t < 64) {
    wsf[OFF_B0F + t] = b0[t];
    wsf[OFF_S1F + t] = g1[t] * rs;
    wsf[OFF_B1F + t] = b1[t];
  }
  if (t < 192) wsf[OFF_WOUTS + t] = wout[t] * (gout[t / 64] * rs);
  if (t < 3) wsf[OFF_BOUTF + t] = bout[t];
  // pack xq = (x0, x1, x2, ||x||^2)
  if (t < BATCH * NPTS) {
    int bb = t >> 12, j = t & (NPTS - 1);
    const float* xb = x + bb * 3 * NPTS;
    float x0 = xb[j], x1 = xb[NPTS + j], x2 = xb[2 * NPTS + j];
    float xx = x0 * x0 + x1 * x1 + x2 * x2;
    xq[t] = make_float4(x0, x1, x2, xx);
  }
  // B-fragment layout for mfma_f32_16x16x32_bf16 (as round 3)
  if (t < 24576) {
    int j = t & 7, L = (t >> 3) & 63, ft = t >> 9;
    int kk = ft >> 2, nt = ft & 3;
    int k = kk * 32 + ((L >> 4) << 3) + j;
    int c = k >> 6, d = k & 63;
    int o = nt * 16 + (L & 15);
    float w = w1[(o * 6 + c) * 64 + d];
    unsigned bw = __float_as_uint(w);
    unsigned hb = bw & 0xFFFF0000u;
    float r = w - __uint_as_float(hb);
    whi[t] = (unsigned short)(bw >> 16);
    wlo[t] = (unsigned short)(__float_as_uint(r) >> 16);
  }
}

// knn v2: no LDS. Each lane owns 64 candidates (j = s*64 + lane), scanned ONCE
// into a register top-2 cache of packed sort keys:
//   key = (~bits(pd) << 32) | (4095 - j)
// (pd <= 0 in exact arithmetic -> ~bits is order-preserving; self-point pd=+0.0
//  maps to the global max key, matching top_k. Larger low-word = smaller j =
//  lax.top_k tie-break.)
// Then 20 rounds of u64 butterfly argmax; winner's owner pops its cache. A
// per-lane taken-bitmap + rare cooperative rescan (lane wins 3+ times) keeps
// it exact.
__global__ __launch_bounds__(64, 4) void knn_kernel(const float4* __restrict__ xq,
                                                    unsigned short* __restrict__ idxbuf) {
  const int pt = blockIdx.x;
  const int b = pt >> 12, n = pt & (NPTS - 1);
  const int lane = threadIdx.x;
  const float4* xqb = xq + b * NPTS;
  const float4 xin = xqb[n];
  const float xi0 = xin.x, xi1 = xin.y, xi2 = xin.z;
  const float nxxi = -xin.w;

  // phase A: single scan, build top-2 cache
  u64 k1 = 0, k2 = 0;
  unsigned lo = 4095u - (unsigned)lane;   // = 4095 - (s*64 + lane), decremented by 64/iter
#pragma unroll 4
  for (int s = 0; s < 64; ++s) {
    float4 q = xqb[s * 64 + lane];
    float dot = xi0 * q.x + xi1 * q.y + xi2 * q.z;
    float inner = -2.0f * dot;
    float pd = (nxxi - inner) - q.w;      // same expression as reference path
    u64 k = ((u64)(~__float_as_uint(pd)) << 32) | lo;
    lo -= 64u;
    bool c1 = k > k1;
    bool c2 = k > k2;
    u64 t = c1 ? k1 : k;
    k2 = c2 ? t : k2;
    k1 = c1 ? k : k1;
  }

  // phase B: 20 rounds of global argmax + pop
  u64 tk = 0;          // taken bitmap over my 64 slots (bit s)
  unsigned myout = 0;  // lane r holds round-r winner
#pragma unroll 1
  for (int r = 0; r < KNN; ++r) {
    u64 bk = k1;
    for (int off = 32; off > 0; off >>= 1) {
      u64 ok = shflx64(bk, off);
      if (ok > bk) bk = ok;
    }
    unsigned bj = 4095u - (unsigned)(bk & 4095u);
    if (lane == r) myout = bj;
    bool owner = (k1 == bk);             // keys unique -> exactly one owner
    u64 bit = 1ull << (bj >> 6);
    if (owner) {
      tk |= bit;
      k1 = k2;
      k2 = 0;
    }
    bool need = owner && (k1 == 0);
    u64 nm = __ballot(need);
    if (nm) {                            // rare: a lane exhausted its cache
      int LN = __ffsll(nm) - 1;
      int j2 = lane * 64 + LN;           // lane s rescans slot s of lane LN
      float4 q = xqb[j2];
      float dot = xi0 * q.x + xi1 * q.y + xi2 * q.z;
      float inner = -2.0f * dot;
      float pd = (nxxi - inner) - q.w;
      u64 kk = ((u64)(~__float_as_uint(pd)) << 32) | (4095u - (unsigned)j2);
      u64 tkl = shflbc64(tk, LN);
      if ((tkl >> lane) & 1) kk = 0;     // exclude already-taken
      u64 w1k = kk;
      for (int off = 32; off > 0; off >>= 1) {
        u64 ok = shflx64(w1k, off);
        if (ok > w1k) w1k = ok;
      }
      u64 kk2 = (kk == w1k) ? 0 : kk;
      u64 w2k = kk2;
      for (int off = 32; off > 0; off >>= 1) {
        u64 ok = shflx64(w2k, off);
        if (ok > w2k) w2k = ok;
      }
      if (lane == LN) { k1 = w1k; k2 = w2k; }
    }
  }
  if (lane < KNN) idxbuf[pt * KNN + lane] = (unsigned short)myout;
}

// MFMA mlp (unchanged from round 3)
__global__ __launch_bounds__(64) void mlp_kernel(const float* __restrict__ x,
                                                 const float* __restrict__ wsf,
                                                 const unsigned short* __restrict__ whi,
                                                 const unsigned short* __restrict__ wlo,
                                                 const unsigned short* __restrict__ idxbuf,
                                                 float* __restrict__ out) {
  __shared__ float smem[80 * 68 + 80 * 8];
  float* h_lds = smem;
  float* v6_lds = smem + 80 * 68;
  float* pmax = smem;

  const int lane = threadIdx.x;
  const int quad = lane >> 4, l15 = lane & 15;
  const int pt_base = blockIdx.x * 4;

  const float w0r0 = wsf[OFF_W0S + lane * 6 + 0];
  const float w0r1 = wsf[OFF_W0S + lane * 6 + 1];
  const float w0r2 = wsf[OFF_W0S + lane * 6 + 2];
  const float w0r3 = wsf[OFF_W0S + lane * 6 + 3];
  const float w0r4 = wsf[OFF_W0S + lane * 6 + 4];
  const float w0r5 = wsf[OFF_W0S + lane * 6 + 5];
  const float b0r = wsf[OFF_B0F + lane];
  float s1v[4], b1v[4];
#pragma unroll
  for (int nt = 0; nt < 4; ++nt) {
    s1v[nt] = wsf[OFF_S1F + nt * 16 + l15];
    b1v[nt] = wsf[OFF_B1F + nt * 16 + l15];
  }
  float woutr[3];
#pragma unroll
  for (int m = 0; m < 3; ++m) woutr[m] = wsf[OFF_WOUTS + m * 64 + lane];

#pragma unroll
  for (int rep = 0; rep < 2; ++rep) {
    int e = rep * 64 + lane;
    if (e < 80) {
      int p = e / 20;
      int el = e - p * 20;
      int pt = pt_base + p;
      int b = pt >> 12, n = pt & (NPTS - 1);
      const float* xb = x + b * 3 * NPTS;
      float xi0 = xb[n], xi1 = xb[NPTS + n], xi2 = xb[2 * NPTS + n];
      int jn = idxbuf[pt * KNN + el];
      float xj0 = xb[jn], xj1 = xb[NPTS + jn], xj2 = xb[2 * NPTS + jn];
      v6_lds[e * 8 + 0] = xj0 - xi0;
      v6_lds[e * 8 + 1] = xj1 - xi1;
      v6_lds[e * 8 + 2] = xj2 - xi2;
      v6_lds[e * 8 + 3] = xi0;
      v6_lds[e * 8 + 4] = xi1;
      v6_lds[e * 8 + 5] = xi2;
    }
  }
  __syncthreads();

#pragma unroll 4
  for (int e = 0; e < 80; ++e) {
    f32x4 va = *(const f32x4*)(v6_lds + e * 8);
    float c4 = v6_lds[e * 8 + 4], c5 = v6_lds[e * 8 + 5];
    float acc = b0r + w0r0 * va.x + w0r1 * va.y + w0r2 * va.z + w0r3 * va.w + w0r4 * c4 + w0r5 * c5;
    h_lds[e * 68 + lane] = fmaxf(acc, 0.2f * acc);
  }
  __syncthreads();

  f32x4 acc[5][4];
#pragma unroll
  for (int t = 0; t < 5; ++t)
#pragma unroll
    for (int nt = 0; nt < 4; ++nt) acc[t][nt] = (f32x4){0.f, 0.f, 0.f, 0.f};

  const i32x4* whp = (const i32x4*)whi;
  const i32x4* wlp = (const i32x4*)wlo;
  i32x4 wh[4], wl[4];
#pragma unroll
  for (int nt = 0; nt < 4; ++nt) {
    wh[nt] = whp[nt * 64 + lane];
    wl[nt] = wlp[nt * 64 + lane];
  }

#pragma unroll 2
  for (int kk = 0; kk < 12; ++kk) {
    i32x4 whn[4], wln[4];
    if (kk < 11) {
#pragma unroll
      for (int nt = 0; nt < 4; ++nt) {
        whn[nt] = whp[((kk + 1) * 4 + nt) * 64 + lane];
        wln[nt] = wlp[((kk + 1) * 4 + nt) * 64 + lane];
      }
    }
    const int c = kk >> 1;
    const int d0 = (kk & 1) * 32 + quad * 8;
#pragma unroll
    for (int t = 0; t < 5; ++t) {
      const int m = t * 16 + l15;
      const float* hp = h_lds + m * 68 + d0;
      f32x4 h0 = *(const f32x4*)hp;
      f32x4 h1 = *(const f32x4*)(hp + 4);
      float vc = v6_lds[m * 8 + c];
      float u0 = vc * h0.x, u1 = vc * h0.y, u2 = vc * h0.z, u3 = vc * h0.w;
      float u4 = vc * h1.x, u5 = vc * h1.y, u6 = vc * h1.z, u7 = vc * h1.w;
      unsigned ub0 = __float_as_uint(u0), ub1 = __float_as_uint(u1);
      unsigned ub2 = __float_as_uint(u2), ub3 = __float_as_uint(u3);
      unsigned ub4 = __float_as_uint(u4), ub5 = __float_as_uint(u5);
      unsigned ub6 = __float_as_uint(u6), ub7 = __float_as_uint(u7);
      float r0 = u0 - __uint_as_float(ub0 & 0xFFFF0000u);
      float r1 = u1 - __uint_as_float(ub1 & 0xFFFF0000u);
      float r2 = u2 - __uint_as_float(ub2 & 0xFFFF0000u);
      float r3 = u3 - __uint_as_float(ub3 & 0xFFFF0000u);
      float r4 = u4 - __uint_as_float(ub4 & 0xFFFF0000u);
      float r5 = u5 - __uint_as_float(ub5 & 0xFFFF0000u);
      float r6 = u6 - __uint_as_float(ub6 & 0xFFFF0000u);
      float r7 = u7 - __uint_as_float(ub7 & 0xFFFF0000u);
      i32x4 ah, al;
      ah.x = __builtin_amdgcn_perm(ub1, ub0, 0x07060302);
      ah.y = __builtin_amdgcn_perm(ub3, ub2, 0x07060302);
      ah.z = __builtin_amdgcn_perm(ub5, ub4, 0x07060302);
      ah.w = __builtin_amdgcn_perm(ub7, ub6, 0x07060302);
      al.x = __builtin_amdgcn_perm(__float_as_uint(r1), __float_as_uint(r0), 0x07060302);
      al.y = __builtin_amdgcn_perm(__float_as_uint(r3), __float_as_uint(r2), 0x07060302);
      al.z = __builtin_amdgcn_perm(__float_as_uint(r5), __float_as_uint(r4), 0x07060302);
      al.w = __builtin_amdgcn_perm(__float_as_uint(r7), __float_as_uint(r6), 0x07060302);
      bf16x8 ahv = __builtin_bit_cast(bf16x8, ah);
      bf16x8 alv = __builtin_bit_cast(bf16x8, al);
#pragma unroll
      for (int nt = 0; nt < 4; ++nt) {
        bf16x8 bh = __builtin_bit_cast(bf16x8, wh[nt]);
        bf16x8 bl = __builtin_bit_cast(bf16x8, wl[nt]);
        acc[t][nt] = __builtin_amdgcn_mfma_f32_16x16x32_bf16(ahv, bh, acc[t][nt], 0, 0, 0);
        acc[t][nt] = __builtin_amdgcn_mfma_f32_16x16x32_bf16(ahv, bl, acc[t][nt], 0, 0, 0);
        acc[t][nt] = __builtin_amdgcn_mfma_f32_16x16x32_bf16(alv, bh, acc[t][nt], 0, 0, 0);
      }
    }
#pragma unroll
    for (int nt = 0; nt < 4; ++nt) { wh[nt] = whn[nt]; wl[nt] = wln[nt]; }
  }
  __syncthreads();

#pragma unroll
  for (int t = 0; t < 5; ++t) {
#pragma unroll
    for (int nt = 0; nt < 4; ++nt) {
      f32x4 a = acc[t][nt];
      float z0 = a.x * s1v[nt] + b1v[nt]; z0 = fmaxf(z0, 0.2f * z0);
      float z1 = a.y * s1v[nt] + b1v[nt]; z1 = fmaxf(z1, 0.2f * z1);
      float z2 = a.z * s1v[nt] + b1v[nt]; z2 = fmaxf(z2, 0.2f * z2);
      float z3 = a.w * s1v[nt] + b1v[nt]; z3 = fmaxf(z3, 0.2f * z3);
      float m4 = fmaxf(fmaxf(z0, z1), fmaxf(z2, z3));
      pmax[(t * 4 + quad) * 66 + nt * 16 + l15] = m4;
    }
  }
  __syncthreads();

#pragma unroll
  for (int p = 0; p < 4; ++p) {
    float x1 = pmax[(p * 5 + 0) * 66 + lane];
    x1 = fmaxf(x1, pmax[(p * 5 + 1) * 66 + lane]);
    x1 = fmaxf(x1, pmax[(p * 5 + 2) * 66 + lane]);
    x1 = fmaxf(x1, pmax[(p * 5 + 3) * 66 + lane]);
    x1 = fmaxf(x1, pmax[(p * 5 + 4) * 66 + lane]);
    int pt = pt_base + p;
    int b = pt >> 12, n = pt & (NPTS - 1);
#pragma unroll
    for (int m = 0; m < 3; ++m) {
      float part = woutr[m] * x1;
      for (int off = 32; off > 0; off >>= 1) part += __shfl_xor(part, off);
      if (lane == 0) {
        float ov = part + wsf[OFF_BOUTF + m];
        out[(b * 3 + m) * NPTS + n] = fmaxf(ov, 0.2f * ov);
      }
    }
  }
}

extern "C" void kernel_launch(void* const* d_in, const int* in_sizes, int n_in,
                              void* d_out, int out_size, void* d_ws, size_t ws_size,
                              hipStream_t stream) {
  const float* x    = (const float*)d_in[0];
  const float* w0   = (const float*)d_in[1];
  const float* g0   = (const float*)d_in[2];
  const float* b0   = (const float*)d_in[3];
  const float* w1   = (const float*)d_in[4];
  const float* g1   = (const float*)d_in[5];
  const float* b1   = (const float*)d_in[6];
  const float* wout = (const float*)d_in[7];
  const float* gout = (const float*)d_in[8];
  const float* bout = (const float*)d_in[9];
  float* wsf = (float*)d_ws;
  unsigned short* whi = (unsigned short*)((char*)d_ws + OFF_WHI_BYTES);
  unsigned short* wlo = (unsigned short*)((char*)d_ws + OFF_WLO_BYTES);
  unsigned short* idxbuf = (unsigned short*)((char*)d_ws + OFF_IDX_BYTES);
  float4* xq = (float4*)((char*)d_ws + OFF_XQ_BYTES);
  float* out = (float*)d_out;

  prep_kernel<<<96, 256, 0, stream>>>(x, w0, g0, b0, w1, g1, b1, wout, gout, bout,
                                      wsf, whi, wlo, xq);
  knn_kernel<<<BATCH * NPTS, 64, 0, stream>>>(xq, idxbuf);
  mlp_kernel<<<BATCH * NPTS / 4, 64, 0, stream>>>(x, wsf, whi, wlo, idxbuf, out);
}

// Round 5
// 207.987 us; speedup vs baseline: 4.2571x; 1.0545x over previous
//
#include <hip/hip_runtime.h>
#include <hip/hip_bf16.h>

#define NPTS 4096
#define BATCH 4
#define KNN 20

typedef __attribute__((ext_vector_type(8))) short bf16x8;
typedef __attribute__((ext_vector_type(4))) float f32x4;
typedef __attribute__((ext_vector_type(4))) int i32x4;
typedef unsigned long long u64;

// ws layout (bytes):
//   0      : fp32 tables: w0s[384] b0[64] s1[64] b1[64] wouts[192] bout[3]
//   4096   : whi frags ushort[24576]  (B-fragment layout, hi split)
//   53248  : wlo frags ushort[24576]  (lo split)
//   102400 : idxbuf ushort[16384*20]  (655360 B)
//   757760 : xq float4[16384] = (x0,x1,x2,||x||^2)  (262144 B)
#define OFF_W0S   0
#define OFF_B0F   384
#define OFF_S1F   448
#define OFF_B1F   512
#define OFF_WOUTS 576
#define OFF_BOUTF 768
#define OFF_WHI_BYTES 4096
#define OFF_WLO_BYTES 53248
#define OFF_IDX_BYTES 102400
#define OFF_XQ_BYTES  757760

__device__ __forceinline__ u64 shflx64(u64 v, int off) {
  int lo = __shfl_xor((int)(v & 0xFFFFFFFFull), off);
  int hi = __shfl_xor((int)(v >> 32), off);
  return ((u64)(unsigned)hi << 32) | (unsigned)lo;
}
__device__ __forceinline__ u64 shflbc64(u64 v, int src) {
  int lo = __shfl((int)(v & 0xFFFFFFFFull), src);
  int hi = __shfl((int)(v >> 32), src);
  return ((u64)(unsigned)hi << 32) | (unsigned)lo;
}

__global__ __launch_bounds__(256) void prep_kernel(
    const float* __restrict__ x,
    const float* __restrict__ w0, const float* __restrict__ g0, const float* __restrict__ b0,
    const float* __restrict__ w1, const float* __restrict__ g1, const float* __restrict__ b1,
    const float* __restrict__ wout, const float* __restrict__ gout, const float* __restrict__ bout,
    float* __restrict__ wsf, unsigned short* __restrict__ whi, unsigned short* __restrict__ wlo,
    float4* __restrict__ xq) {
  const float rs = 1.0f / sqrtf(1.0f + 1e-5f);
  int t = blockIdx.x * 256 + threadIdx.x;
  if (t < 384) wsf[OFF_W0S + t] = w0[t] * (g0[t / 6] * rs);
  if (t < 64) {
    wsf[OFF_B0F + t] = b0[t];
    wsf[OFF_S1F + t] = g1[t] * rs;
    wsf[OFF_B1F + t] = b1[t];
  }
  if (t < 192) wsf[OFF_WOUTS + t] = wout[t] * (gout[t / 64] * rs);
  if (t < 3) wsf[OFF_BOUTF + t] = bout[t];
  if (t < BATCH * NPTS) {
    int bb = t >> 12, j = t & (NPTS - 1);
    const float* xb = x + bb * 3 * NPTS;
    float x0 = xb[j], x1 = xb[NPTS + j], x2 = xb[2 * NPTS + j];
    float xx = x0 * x0 + x1 * x1 + x2 * x2;
    xq[t] = make_float4(x0, x1, x2, xx);
  }
  // B-fragment layout for mfma_f32_16x16x32_bf16: frag ft = kk*4+nt; lane L holds
  // B[k = kk*32 + (L>>4)*8 + j][n = nt*16 + (L&15)], j packed consecutively.
  if (t < 24576) {
    int j = t & 7, L = (t >> 3) & 63, ft = t >> 9;
    int kk = ft >> 2, nt = ft & 3;
    int k = kk * 32 + ((L >> 4) << 3) + j;
    int c = k >> 6, d = k & 63;
    int o = nt * 16 + (L & 15);
    float w = w1[(o * 6 + c) * 64 + d];
    unsigned bw = __float_as_uint(w);
    unsigned hb = bw & 0xFFFF0000u;
    float r = w - __uint_as_float(hb);
    whi[t] = (unsigned short)(bw >> 16);
    wlo[t] = (unsigned short)(__float_as_uint(r) >> 16);
  }
}

// knn (unchanged from round 4): single-scan register top-2 cache + butterfly argmax.
__global__ __launch_bounds__(64, 4) void knn_kernel(const float4* __restrict__ xq,
                                                    unsigned short* __restrict__ idxbuf) {
  const int pt = blockIdx.x;
  const int b = pt >> 12, n = pt & (NPTS - 1);
  const int lane = threadIdx.x;
  const float4* xqb = xq + b * NPTS;
  const float4 xin = xqb[n];
  const float xi0 = xin.x, xi1 = xin.y, xi2 = xin.z;
  const float nxxi = -xin.w;

  u64 k1 = 0, k2 = 0;
  unsigned lo = 4095u - (unsigned)lane;
#pragma unroll 4
  for (int s = 0; s < 64; ++s) {
    float4 q = xqb[s * 64 + lane];
    float dot = xi0 * q.x + xi1 * q.y + xi2 * q.z;
    float inner = -2.0f * dot;
    float pd = (nxxi - inner) - q.w;
    u64 k = ((u64)(~__float_as_uint(pd)) << 32) | lo;
    lo -= 64u;
    bool c1 = k > k1;
    bool c2 = k > k2;
    u64 t = c1 ? k1 : k;
    k2 = c2 ? t : k2;
    k1 = c1 ? k : k1;
  }

  u64 tk = 0;
  unsigned myout = 0;
#pragma unroll 1
  for (int r = 0; r < KNN; ++r) {
    u64 bk = k1;
    for (int off = 32; off > 0; off >>= 1) {
      u64 ok = shflx64(bk, off);
      if (ok > bk) bk = ok;
    }
    unsigned bj = 4095u - (unsigned)(bk & 4095u);
    if (lane == r) myout = bj;
    bool owner = (k1 == bk);
    u64 bit = 1ull << (bj >> 6);
    if (owner) {
      tk |= bit;
      k1 = k2;
      k2 = 0;
    }
    bool need = owner && (k1 == 0);
    u64 nm = __ballot(need);
    if (nm) {
      int LN = __ffsll(nm) - 1;
      int j2 = lane * 64 + LN;
      float4 q = xqb[j2];
      float dot = xi0 * q.x + xi1 * q.y + xi2 * q.z;
      float inner = -2.0f * dot;
      float pd = (nxxi - inner) - q.w;
      u64 kk = ((u64)(~__float_as_uint(pd)) << 32) | (4095u - (unsigned)j2);
      u64 tkl = shflbc64(tk, LN);
      if ((tkl >> lane) & 1) kk = 0;
      u64 w1k = kk;
      for (int off = 32; off > 0; off >>= 1) {
        u64 ok = shflx64(w1k, off);
        if (ok > w1k) w1k = ok;
      }
      u64 kk2 = (kk == w1k) ? 0 : kk;
      u64 w2k = kk2;
      for (int off = 32; off > 0; off >>= 1) {
        u64 ok = shflx64(w2k, off);
        if (ok > w2k) w2k = ok;
      }
      if (lane == LN) { k1 = w1k; k2 = w2k; }
    }
  }
  if (lane < KNN) idxbuf[pt * KNN + lane] = (unsigned short)myout;
}

// mlp v3: 1 wave = 4 points = 80 edges = 5 M-tiles. h-fragments computed
// DIRECTLY per lane in registers (each (e,d) maps to exactly one lane in the
// MFMA A-layout) -> no h LDS, no transpose reads. k-loop = pure B-prefetch +
// u-split + MFMA. LDS: w0 tables (448 f) + v6 (80x12 f) + pmax (20x66 f).
__global__ __launch_bounds__(64, 2) void mlp_kernel(const float4* __restrict__ xq,
                                                    const float* __restrict__ wsf,
                                                    const unsigned short* __restrict__ whi,
                                                    const unsigned short* __restrict__ wlo,
                                                    const unsigned short* __restrict__ idxbuf,
                                                    float* __restrict__ out) {
  __shared__ float w0l[448];        // w0s[384] + b0[64]
  __shared__ float v6l[80 * 12];    // stride 12: b128-aligned, 2-way banks (free)
  __shared__ float pmax[20 * 66];

  const int lane = threadIdx.x;
  const int quad = lane >> 4, l15 = lane & 15;
  const int pt_base = blockIdx.x * 4;

  for (int i = lane; i < 448; i += 64) w0l[i] = wsf[i];

  // stage 1: v6 per edge (xq packed loads: 2 dwordx4 per edge)
#pragma unroll
  for (int rep = 0; rep < 2; ++rep) {
    int e = rep * 64 + lane;
    if (e < 80) {
      int p = e / 20, el = e - p * 20;
      int pt = pt_base + p;
      int b = pt >> 12, n = pt & (NPTS - 1);
      float4 xi = xq[b * NPTS + n];
      int jn = idxbuf[pt * KNN + el];
      float4 xj = xq[b * NPTS + jn];
      v6l[e * 12 + 0] = xj.x - xi.x;
      v6l[e * 12 + 1] = xj.y - xi.y;
      v6l[e * 12 + 2] = xj.z - xi.z;
      v6l[e * 12 + 3] = xi.x;
      v6l[e * 12 + 4] = xi.y;
      v6l[e * 12 + 5] = xi.z;
    }
  }
  __syncthreads();

  // stage 2: per-lane h fragments. Lane needs h[e=t*16+l15][d=hh*32+quad*8+j];
  // each (e,d) is computed by exactly one lane (no redundancy, no LDS h).
  float v6r[5][6];
#pragma unroll
  for (int t = 0; t < 5; ++t) {
    const float* vr = v6l + (t * 16 + l15) * 12;
    f32x4 a4 = *(const f32x4*)vr;
    v6r[t][0] = a4.x; v6r[t][1] = a4.y; v6r[t][2] = a4.z; v6r[t][3] = a4.w;
    v6r[t][4] = vr[4]; v6r[t][5] = vr[5];
  }
  float hf[5][2][8];
#pragma unroll
  for (int hh = 0; hh < 2; ++hh) {
#pragma unroll
    for (int j = 0; j < 8; ++j) {
      const int d = hh * 32 + quad * 8 + j;
      const float* wr = w0l + d * 6;
      float wc0 = wr[0], wc1 = wr[1], wc2 = wr[2];
      float wc3 = wr[3], wc4 = wr[4], wc5 = wr[5];
      float bb = w0l[384 + d];
#pragma unroll
      for (int t = 0; t < 5; ++t) {
        float a = bb + wc0 * v6r[t][0] + wc1 * v6r[t][1] + wc2 * v6r[t][2]
                     + wc3 * v6r[t][3] + wc4 * v6r[t][4] + wc5 * v6r[t][5];
        hf[t][hh][j] = fmaxf(a, 0.2f * a);
      }
    }
  }

  // k-loop: 12 steps of K=32, fully unrolled (c, hh become constants)
  f32x4 acc[5][4];
#pragma unroll
  for (int t = 0; t < 5; ++t)
#pragma unroll
    for (int nt = 0; nt < 4; ++nt) acc[t][nt] = (f32x4){0.f, 0.f, 0.f, 0.f};

  const i32x4* whp = (const i32x4*)whi;
  const i32x4* wlp = (const i32x4*)wlo;

#pragma unroll
  for (int kk = 0; kk < 12; ++kk) {
    const int c = kk >> 1, hh = kk & 1;
    i32x4 wh[4], wl[4];
#pragma unroll
    for (int nt = 0; nt < 4; ++nt) {
      wh[nt] = whp[(kk * 4 + nt) * 64 + lane];
      wl[nt] = wlp[(kk * 4 + nt) * 64 + lane];
    }
#pragma unroll
    for (int t = 0; t < 5; ++t) {
      float vc = v6l[(t * 16 + l15) * 12 + c];   // LDS re-read: keeps VGPRs low
      float u0 = vc * hf[t][hh][0], u1 = vc * hf[t][hh][1];
      float u2 = vc * hf[t][hh][2], u3 = vc * hf[t][hh][3];
      float u4 = vc * hf[t][hh][4], u5 = vc * hf[t][hh][5];
      float u6 = vc * hf[t][hh][6], u7 = vc * hf[t][hh][7];
      unsigned ub0 = __float_as_uint(u0), ub1 = __float_as_uint(u1);
      unsigned ub2 = __float_as_uint(u2), ub3 = __float_as_uint(u3);
      unsigned ub4 = __float_as_uint(u4), ub5 = __float_as_uint(u5);
      unsigned ub6 = __float_as_uint(u6), ub7 = __float_as_uint(u7);
      float r0 = u0 - __uint_as_float(ub0 & 0xFFFF0000u);
      float r1 = u1 - __uint_as_float(ub1 & 0xFFFF0000u);
      float r2 = u2 - __uint_as_float(ub2 & 0xFFFF0000u);
      float r3 = u3 - __uint_as_float(ub3 & 0xFFFF0000u);
      float r4 = u4 - __uint_as_float(ub4 & 0xFFFF0000u);
      float r5 = u5 - __uint_as_float(ub5 & 0xFFFF0000u);
      float r6 = u6 - __uint_as_float(ub6 & 0xFFFF0000u);
      float r7 = u7 - __uint_as_float(ub7 & 0xFFFF0000u);
      i32x4 ah, al;
      ah.x = __builtin_amdgcn_perm(ub1, ub0, 0x07060302);
      ah.y = __builtin_amdgcn_perm(ub3, ub2, 0x07060302);
      ah.z = __builtin_amdgcn_perm(ub5, ub4, 0x07060302);
      ah.w = __builtin_amdgcn_perm(ub7, ub6, 0x07060302);
      al.x = __builtin_amdgcn_perm(__float_as_uint(r1), __float_as_uint(r0), 0x07060302);
      al.y = __builtin_amdgcn_perm(__float_as_uint(r3), __float_as_uint(r2), 0x07060302);
      al.z = __builtin_amdgcn_perm(__float_as_uint(r5), __float_as_uint(r4), 0x07060302);
      al.w = __builtin_amdgcn_perm(__float_as_uint(r7), __float_as_uint(r6), 0x07060302);
      bf16x8 ahv = __builtin_bit_cast(bf16x8, ah);
      bf16x8 alv = __builtin_bit_cast(bf16x8, al);
#pragma unroll
      for (int nt = 0; nt < 4; ++nt) {
        bf16x8 bh = __builtin_bit_cast(bf16x8, wh[nt]);
        bf16x8 bl = __builtin_bit_cast(bf16x8, wl[nt]);
        acc[t][nt] = __builtin_amdgcn_mfma_f32_16x16x32_bf16(ahv, bh, acc[t][nt], 0, 0, 0);
        acc[t][nt] = __builtin_amdgcn_mfma_f32_16x16x32_bf16(ahv, bl, acc[t][nt], 0, 0, 0);
        acc[t][nt] = __builtin_amdgcn_mfma_f32_16x16x32_bf16(alv, bh, acc[t][nt], 0, 0, 0);
      }
    }
  }
  __syncthreads();

  // epilogue: BN + lrelu, quad-local max (4 edges of one point), pmax transpose
  float s1v[4], b1v[4];
#pragma unroll
  for (int nt = 0; nt < 4; ++nt) {
    s1v[nt] = wsf[OFF_S1F + nt * 16 + l15];
    b1v[nt] = wsf[OFF_B1F + nt * 16 + l15];
  }
#pragma unroll
  for (int t = 0; t < 5; ++t) {
#pragma unroll
    for (int nt = 0; nt < 4; ++nt) {
      f32x4 a = acc[t][nt];
      float z0 = a.x * s1v[nt] + b1v[nt]; z0 = fmaxf(z0, 0.2f * z0);
      float z1 = a.y * s1v[nt] + b1v[nt]; z1 = fmaxf(z1, 0.2f * z1);
      float z2 = a.z * s1v[nt] + b1v[nt]; z2 = fmaxf(z2, 0.2f * z2);
      float z3 = a.w * s1v[nt] + b1v[nt]; z3 = fmaxf(z3, 0.2f * z3);
      float m4 = fmaxf(fmaxf(z0, z1), fmaxf(z2, z3));
      pmax[(t * 4 + quad) * 66 + nt * 16 + l15] = m4;
    }
  }
  __syncthreads();

  float woutr[3];
#pragma unroll
  for (int m = 0; m < 3; ++m) woutr[m] = wsf[OFF_WOUTS + m * 64 + lane];
#pragma unroll
  for (int p = 0; p < 4; ++p) {
    float x1 = pmax[(p * 5 + 0) * 66 + lane];
    x1 = fmaxf(x1, pmax[(p * 5 + 1) * 66 + lane]);
    x1 = fmaxf(x1, pmax[(p * 5 + 2) * 66 + lane]);
    x1 = fmaxf(x1, pmax[(p * 5 + 3) * 66 + lane]);
    x1 = fmaxf(x1, pmax[(p * 5 + 4) * 66 + lane]);
    int pt = pt_base + p;
    int b = pt >> 12, n = pt & (NPTS - 1);
#pragma unroll
    for (int m = 0; m < 3; ++m) {
      float part = woutr[m] * x1;
      for (int off = 32; off > 0; off >>= 1) part += __shfl_xor(part, off);
      if (lane == 0) {
        float ov = part + wsf[OFF_BOUTF + m];
        out[(b * 3 + m) * NPTS + n] = fmaxf(ov, 0.2f * ov);
      }
    }
  }
}

extern "C" void kernel_launch(void* const* d_in, const int* in_sizes, int n_in,
                              void* d_out, int out_size, void* d_ws, size_t ws_size,
                              hipStream_t stream) {
  const float* x    = (const float*)d_in[0];
  const float* w0   = (const float*)d_in[1];
  const float* g0   = (const float*)d_in[2];
  const float* b0   = (const float*)d_in[3];
  const float* w1   = (const float*)d_in[4];
  const float* g1   = (const float*)d_in[5];
  const float* b1   = (const float*)d_in[6];
  const float* wout = (const float*)d_in[7];
  const float* gout = (const float*)d_in[8];
  const float* bout = (const float*)d_in[9];
  float* wsf = (float*)d_ws;
  unsigned short* whi = (unsigned short*)((char*)d_ws + OFF_WHI_BYTES);
  unsigned short* wlo = (unsigned short*)((char*)d_ws + OFF_WLO_BYTES);
  unsigned short* idxbuf = (unsigned short*)((char*)d_ws + OFF_IDX_BYTES);
  float4* xq = (float4*)((char*)d_ws + OFF_XQ_BYTES);
  float* out = (float*)d_out;

  prep_kernel<<<96, 256, 0, stream>>>(x, w0, g0, b0, w1, g1, b1, wout, gout, bout,
                                      wsf, whi, wlo, xq);
  knn_kernel<<<BATCH * NPTS, 64, 0, stream>>>(xq, idxbuf);
  mlp_kernel<<<BATCH * NPTS / 4, 64, 0, stream>>>(xq, wsf, whi, wlo, idxbuf, out);
}

// Round 6
// 188.955 us; speedup vs baseline: 4.6859x; 1.1007x over previous
//
#include <hip/hip_runtime.h>
#include <hip/hip_bf16.h>

#define NPTS 4096
#define BATCH 4
#define KNN 20

typedef __attribute__((ext_vector_type(8))) short bf16x8;
typedef __attribute__((ext_vector_type(4))) float f32x4;
typedef __attribute__((ext_vector_type(4))) int i32x4;
typedef unsigned long long u64;

// ws layout (bytes):
//   0      : fp32 tables: w0s[384] b0[64] s1[64] b1[64] wouts[192] bout[3]
//   4096   : whi frags ushort[24576]  (B-fragment layout, hi split)
//   53248  : wlo frags ushort[24576]  (lo split)
//   102400 : idxbuf ushort[16384*20]  (655360 B)
//   757760 : xq float4[16384] = (x0,x1,x2,||x||^2)  (262144 B)
#define OFF_W0S   0
#define OFF_B0F   384
#define OFF_S1F   448
#define OFF_B1F   512
#define OFF_WOUTS 576
#define OFF_BOUTF 768
#define OFF_WHI_BYTES 4096
#define OFF_WLO_BYTES 53248
#define OFF_IDX_BYTES 102400
#define OFF_XQ_BYTES  757760

__device__ __forceinline__ u64 shflx64(u64 v, int off) {
  int lo = __shfl_xor((int)(v & 0xFFFFFFFFull), off);
  int hi = __shfl_xor((int)(v >> 32), off);
  return ((u64)(unsigned)hi << 32) | (unsigned)lo;
}
__device__ __forceinline__ u64 shflbc64(u64 v, int src) {
  int lo = __shfl((int)(v & 0xFFFFFFFFull), src);
  int hi = __shfl((int)(v >> 32), src);
  return ((u64)(unsigned)hi << 32) | (unsigned)lo;
}

__global__ __launch_bounds__(256) void prep_kernel(
    const float* __restrict__ x,
    const float* __restrict__ w0, const float* __restrict__ g0, const float* __restrict__ b0,
    const float* __restrict__ w1, const float* __restrict__ g1, const float* __restrict__ b1,
    const float* __restrict__ wout, const float* __restrict__ gout, const float* __restrict__ bout,
    float* __restrict__ wsf, unsigned short* __restrict__ whi, unsigned short* __restrict__ wlo,
    float4* __restrict__ xq) {
  const float rs = 1.0f / sqrtf(1.0f + 1e-5f);
  int t = blockIdx.x * 256 + threadIdx.x;
  if (t < 384) wsf[OFF_W0S + t] = w0[t] * (g0[t / 6] * rs);
  if (t < 64) {
    wsf[OFF_B0F + t] = b0[t];
    wsf[OFF_S1F + t] = g1[t] * rs;
    wsf[OFF_B1F + t] = b1[t];
  }
  if (t < 192) wsf[OFF_WOUTS + t] = wout[t] * (gout[t / 64] * rs);
  if (t < 3) wsf[OFF_BOUTF + t] = bout[t];
  if (t < BATCH * NPTS) {
    int bb = t >> 12, j = t & (NPTS - 1);
    const float* xb = x + bb * 3 * NPTS;
    float x0 = xb[j], x1 = xb[NPTS + j], x2 = xb[2 * NPTS + j];
    float xx = x0 * x0 + x1 * x1 + x2 * x2;
    xq[t] = make_float4(x0, x1, x2, xx);
  }
  // B-fragment layout for mfma_f32_16x16x32_bf16: frag ft = kk*4+nt; lane L holds
  // B[k = kk*32 + (L>>4)*8 + j][n = nt*16 + (L&15)], j packed consecutively.
  if (t < 24576) {
    int j = t & 7, L = (t >> 3) & 63, ft = t >> 9;
    int kk = ft >> 2, nt = ft & 3;
    int k = kk * 32 + ((L >> 4) << 3) + j;
    int c = k >> 6, d = k & 63;
    int o = nt * 16 + (L & 15);
    float w = w1[(o * 6 + c) * 64 + d];
    unsigned bw = __float_as_uint(w);
    unsigned hb = bw & 0xFFFF0000u;
    float r = w - __uint_as_float(hb);
    whi[t] = (unsigned short)(bw >> 16);
    wlo[t] = (unsigned short)(__float_as_uint(r) >> 16);
  }
}

// knn (unchanged, round-5 control): single-scan register top-2 cache + butterfly argmax.
__global__ __launch_bounds__(64, 4) void knn_kernel(const float4* __restrict__ xq,
                                                    unsigned short* __restrict__ idxbuf) {
  const int pt = blockIdx.x;
  const int b = pt >> 12, n = pt & (NPTS - 1);
  const int lane = threadIdx.x;
  const float4* xqb = xq + b * NPTS;
  const float4 xin = xqb[n];
  const float xi0 = xin.x, xi1 = xin.y, xi2 = xin.z;
  const float nxxi = -xin.w;

  u64 k1 = 0, k2 = 0;
  unsigned lo = 4095u - (unsigned)lane;
#pragma unroll 4
  for (int s = 0; s < 64; ++s) {
    float4 q = xqb[s * 64 + lane];
    float dot = xi0 * q.x + xi1 * q.y + xi2 * q.z;
    float inner = -2.0f * dot;
    float pd = (nxxi - inner) - q.w;
    u64 k = ((u64)(~__float_as_uint(pd)) << 32) | lo;
    lo -= 64u;
    bool c1 = k > k1;
    bool c2 = k > k2;
    u64 t = c1 ? k1 : k;
    k2 = c2 ? t : k2;
    k1 = c1 ? k : k1;
  }

  u64 tk = 0;
  unsigned myout = 0;
#pragma unroll 1
  for (int r = 0; r < KNN; ++r) {
    u64 bk = k1;
    for (int off = 32; off > 0; off >>= 1) {
      u64 ok = shflx64(bk, off);
      if (ok > bk) bk = ok;
    }
    unsigned bj = 4095u - (unsigned)(bk & 4095u);
    if (lane == r) myout = bj;
    bool owner = (k1 == bk);
    u64 bit = 1ull << (bj >> 6);
    if (owner) {
      tk |= bit;
      k1 = k2;
      k2 = 0;
    }
    bool need = owner && (k1 == 0);
    u64 nm = __ballot(need);
    if (nm) {
      int LN = __ffsll(nm) - 1;
      int j2 = lane * 64 + LN;
      float4 q = xqb[j2];
      float dot = xi0 * q.x + xi1 * q.y + xi2 * q.z;
      float inner = -2.0f * dot;
      float pd = (nxxi - inner) - q.w;
      u64 kk = ((u64)(~__float_as_uint(pd)) << 32) | (4095u - (unsigned)j2);
      u64 tkl = shflbc64(tk, LN);
      if ((tkl >> lane) & 1) kk = 0;
      u64 w1k = kk;
      for (int off = 32; off > 0; off >>= 1) {
        u64 ok = shflx64(w1k, off);
        if (ok > w1k) w1k = ok;
      }
      u64 kk2 = (kk == w1k) ? 0 : kk;
      u64 w2k = kk2;
      for (int off = 32; off > 0; off >>= 1) {
        u64 ok = shflx64(w2k, off);
        if (ok > w2k) w2k = ok;
      }
      if (lane == LN) { k1 = w1k; k2 = w2k; }
    }
  }
  if (lane < KNN) idxbuf[pt * KNN + lane] = (unsigned short)myout;
}

// mlp v4: register-pressure-controlled. hh-outer K-order (kk = cc*2 + hh) so the
// live h-fragment set is 40 regs (recomputed per hh, cheap). Explicit B
// double-buffer (+unroll 1 on cc) stops the scheduler from hoisting all 96
// B-loads (v3's suspected spill cause). Peak live ~225 regs -> 2 waves/SIMD,
// no scratch.
__global__ __launch_bounds__(64, 2) void mlp_kernel(const float4* __restrict__ xq,
                                                    const float* __restrict__ wsf,
                                                    const unsigned short* __restrict__ whi,
                                                    const unsigned short* __restrict__ wlo,
                                                    const unsigned short* __restrict__ idxbuf,
                                                    float* __restrict__ out) {
  __shared__ float w0l[448];        // w0s[384] + b0[64]
  __shared__ float v6l[80 * 12];    // stride 12: b128-aligned, conflict-free reads
  __shared__ float pmax[20 * 66];

  const int lane = threadIdx.x;
  const int quad = lane >> 4, l15 = lane & 15;
  const int pt_base = blockIdx.x * 4;

  const i32x4* whp = (const i32x4*)whi;
  const i32x4* wlp = (const i32x4*)wlo;

  // issue first B frag (kk=0) immediately: hidden under the stage-1 gather
  i32x4 wh[4], wl[4];
#pragma unroll
  for (int nt = 0; nt < 4; ++nt) {
    wh[nt] = whp[nt * 64 + lane];          // frag 0*4+nt
    wl[nt] = wlp[nt * 64 + lane];
  }

  for (int i = lane; i < 448; i += 64) w0l[i] = wsf[i];

  // stage 1: v6 per edge
#pragma unroll
  for (int rep = 0; rep < 2; ++rep) {
    int e = rep * 64 + lane;
    if (e < 80) {
      int p = e / 20, el = e - p * 20;
      int pt = pt_base + p;
      int b = pt >> 12, n = pt & (NPTS - 1);
      float4 xi = xq[b * NPTS + n];
      int jn = idxbuf[pt * KNN + el];
      float4 xj = xq[b * NPTS + jn];
      v6l[e * 12 + 0] = xj.x - xi.x;
      v6l[e * 12 + 1] = xj.y - xi.y;
      v6l[e * 12 + 2] = xj.z - xi.z;
      v6l[e * 12 + 3] = xi.x;
      v6l[e * 12 + 4] = xi.y;
      v6l[e * 12 + 5] = xi.z;
    }
  }
  __syncthreads();

  f32x4 acc[5][4];
#pragma unroll
  for (int t = 0; t < 5; ++t)
#pragma unroll
    for (int nt = 0; nt < 4; ++nt) acc[t][nt] = (f32x4){0.f, 0.f, 0.f, 0.f};

#pragma unroll 1
  for (int hh = 0; hh < 2; ++hh) {
    // recompute h fragments for this hh half (d = hh*32 + quad*8 + j)
    float v6r[5][6];
#pragma unroll
    for (int t = 0; t < 5; ++t) {
      const float* vr = v6l + (t * 16 + l15) * 12;
      f32x4 a4 = *(const f32x4*)vr;
      v6r[t][0] = a4.x; v6r[t][1] = a4.y; v6r[t][2] = a4.z; v6r[t][3] = a4.w;
      v6r[t][4] = vr[4]; v6r[t][5] = vr[5];
    }
    float hf[5][8];
#pragma unroll
    for (int j = 0; j < 8; ++j) {
      const int d = hh * 32 + quad * 8 + j;
      const float* wr = w0l + d * 6;
      float wc0 = wr[0], wc1 = wr[1], wc2 = wr[2];
      float wc3 = wr[3], wc4 = wr[4], wc5 = wr[5];
      float bb = w0l[384 + d];
#pragma unroll
      for (int t = 0; t < 5; ++t) {
        float a = bb + wc0 * v6r[t][0] + wc1 * v6r[t][1] + wc2 * v6r[t][2]
                     + wc3 * v6r[t][3] + wc4 * v6r[t][4] + wc5 * v6r[t][5];
        hf[t][j] = fmaxf(a, 0.2f * a);
      }
    }

#pragma unroll 1
    for (int cc = 0; cc < 6; ++cc) {
      const int kk = cc * 2 + hh;
      const bool hasnext = !(hh == 1 && cc == 5);
      const int kkn = (cc < 5) ? kk + 2 : 1;    // cross the hh boundary to kk=1
      i32x4 whn[4], wln[4];
      if (hasnext) {
#pragma unroll
        for (int nt = 0; nt < 4; ++nt) {
          whn[nt] = whp[(kkn * 4 + nt) * 64 + lane];
          wln[nt] = wlp[(kkn * 4 + nt) * 64 + lane];
        }
      }
#pragma unroll
      for (int t = 0; t < 5; ++t) {
        float vc = v6l[(t * 16 + l15) * 12 + cc];   // c == cc
        float u0 = vc * hf[t][0], u1 = vc * hf[t][1];
        float u2 = vc * hf[t][2], u3 = vc * hf[t][3];
        float u4 = vc * hf[t][4], u5 = vc * hf[t][5];
        float u6 = vc * hf[t][6], u7 = vc * hf[t][7];
        unsigned ub0 = __float_as_uint(u0), ub1 = __float_as_uint(u1);
        unsigned ub2 = __float_as_uint(u2), ub3 = __float_as_uint(u3);
        unsigned ub4 = __float_as_uint(u4), ub5 = __float_as_uint(u5);
        unsigned ub6 = __float_as_uint(u6), ub7 = __float_as_uint(u7);
        float r0 = u0 - __uint_as_float(ub0 & 0xFFFF0000u);
        float r1 = u1 - __uint_as_float(ub1 & 0xFFFF0000u);
        float r2 = u2 - __uint_as_float(ub2 & 0xFFFF0000u);
        float r3 = u3 - __uint_as_float(ub3 & 0xFFFF0000u);
        float r4 = u4 - __uint_as_float(ub4 & 0xFFFF0000u);
        float r5 = u5 - __uint_as_float(ub5 & 0xFFFF0000u);
        float r6 = u6 - __uint_as_float(ub6 & 0xFFFF0000u);
        float r7 = u7 - __uint_as_float(ub7 & 0xFFFF0000u);
        i32x4 ah, al;
        ah.x = __builtin_amdgcn_perm(ub1, ub0, 0x07060302);
        ah.y = __builtin_amdgcn_perm(ub3, ub2, 0x07060302);
        ah.z = __builtin_amdgcn_perm(ub5, ub4, 0x07060302);
        ah.w = __builtin_amdgcn_perm(ub7, ub6, 0x07060302);
        al.x = __builtin_amdgcn_perm(__float_as_uint(r1), __float_as_uint(r0), 0x07060302);
        al.y = __builtin_amdgcn_perm(__float_as_uint(r3), __float_as_uint(r2), 0x07060302);
        al.z = __builtin_amdgcn_perm(__float_as_uint(r5), __float_as_uint(r4), 0x07060302);
        al.w = __builtin_amdgcn_perm(__float_as_uint(r7), __float_as_uint(r6), 0x07060302);
        bf16x8 ahv = __builtin_bit_cast(bf16x8, ah);
        bf16x8 alv = __builtin_bit_cast(bf16x8, al);
#pragma unroll
        for (int nt = 0; nt < 4; ++nt) {
          bf16x8 bh = __builtin_bit_cast(bf16x8, wh[nt]);
          bf16x8 bl = __builtin_bit_cast(bf16x8, wl[nt]);
          acc[t][nt] = __builtin_amdgcn_mfma_f32_16x16x32_bf16(ahv, bh, acc[t][nt], 0, 0, 0);
          acc[t][nt] = __builtin_amdgcn_mfma_f32_16x16x32_bf16(ahv, bl, acc[t][nt], 0, 0, 0);
          acc[t][nt] = __builtin_amdgcn_mfma_f32_16x16x32_bf16(alv, bh, acc[t][nt], 0, 0, 0);
        }
      }
      if (hasnext) {
#pragma unroll
        for (int nt = 0; nt < 4; ++nt) { wh[nt] = whn[nt]; wl[nt] = wln[nt]; }
      }
    }
  }
  __syncthreads();

  // epilogue: BN + lrelu, quad-local max (4 edges of one point), pmax transpose
  float s1v[4], b1v[4];
#pragma unroll
  for (int nt = 0; nt < 4; ++nt) {
    s1v[nt] = wsf[OFF_S1F + nt * 16 + l15];
    b1v[nt] = wsf[OFF_B1F + nt * 16 + l15];
  }
#pragma unroll
  for (int t = 0; t < 5; ++t) {
#pragma unroll
    for (int nt = 0; nt < 4; ++nt) {
      f32x4 a = acc[t][nt];
      float z0 = a.x * s1v[nt] + b1v[nt]; z0 = fmaxf(z0, 0.2f * z0);
      float z1 = a.y * s1v[nt] + b1v[nt]; z1 = fmaxf(z1, 0.2f * z1);
      float z2 = a.z * s1v[nt] + b1v[nt]; z2 = fmaxf(z2, 0.2f * z2);
      float z3 = a.w * s1v[nt] + b1v[nt]; z3 = fmaxf(z3, 0.2f * z3);
      float m4 = fmaxf(fmaxf(z0, z1), fmaxf(z2, z3));
      pmax[(t * 4 + quad) * 66 + nt * 16 + l15] = m4;
    }
  }
  __syncthreads();

  float woutr[3];
#pragma unroll
  for (int m = 0; m < 3; ++m) woutr[m] = wsf[OFF_WOUTS + m * 64 + lane];
#pragma unroll
  for (int p = 0; p < 4; ++p) {
    float x1 = pmax[(p * 5 + 0) * 66 + lane];
    x1 = fmaxf(x1, pmax[(p * 5 + 1) * 66 + lane]);
    x1 = fmaxf(x1, pmax[(p * 5 + 2) * 66 + lane]);
    x1 = fmaxf(x1, pmax[(p * 5 + 3) * 66 + lane]);
    x1 = fmaxf(x1, pmax[(p * 5 + 4) * 66 + lane]);
    int pt = pt_base + p;
    int b = pt >> 12, n = pt & (NPTS - 1);
#pragma unroll
    for (int m = 0; m < 3; ++m) {
      float part = woutr[m] * x1;
      for (int off = 32; off > 0; off >>= 1) part += __shfl_xor(part, off);
      if (lane == 0) {
        float ov = part + wsf[OFF_BOUTF + m];
        out[(b * 3 + m) * NPTS + n] = fmaxf(ov, 0.2f * ov);
      }
    }
  }
}

extern "C" void kernel_launch(void* const* d_in, const int* in_sizes, int n_in,
                              void* d_out, int out_size, void* d_ws, size_t ws_size,
                              hipStream_t stream) {
  const float* x    = (const float*)d_in[0];
  const float* w0   = (const float*)d_in[1];
  const float* g0   = (const float*)d_in[2];
  const float* b0   = (const float*)d_in[3];
  const float* w1   = (const float*)d_in[4];
  const float* g1   = (const float*)d_in[5];
  const float* b1   = (const float*)d_in[6];
  const float* wout = (const float*)d_in[7];
  const float* gout = (const float*)d_in[8];
  const float* bout = (const float*)d_in[9];
  float* wsf = (float*)d_ws;
  unsigned short* whi = (unsigned short*)((char*)d_ws + OFF_WHI_BYTES);
  unsigned short* wlo = (unsigned short*)((char*)d_ws + OFF_WLO_BYTES);
  unsigned short* idxbuf = (unsigned short*)((char*)d_ws + OFF_IDX_BYTES);
  float4* xq = (float4*)((char*)d_ws + OFF_XQ_BYTES);
  float* out = (float*)d_out;

  prep_kernel<<<96, 256, 0, stream>>>(x, w0, g0, b0, w1, g1, b1, wout, gout, bout,
                                      wsf, whi, wlo, xq);
  knn_kernel<<<BATCH * NPTS, 64, 0, stream>>>(xq, idxbuf);
  mlp_kernel<<<BATCH * NPTS / 4, 64, 0, stream>>>(xq, wsf, whi, wlo, idxbuf, out);
}